// Round 3
// baseline (106.572 us; speedup 1.0000x reference)
//
#include <hip/hip_runtime.h>

// Cubic Bezier spline evaluation, round 3 (round-2 fix: nontemporal builtins
// need Clang native vector types, not HIP_vector_type structs).
// t: (N,) sorted fp32 in [0,1); ctrl: (S*2, 2) fp32; joint: (S+1, 2) fp32.
// out: (N, 2) fp32.
//
// 2 samples/thread: float2 t-load and float4 out-store are both perfectly
// coalesced. Streaming traffic (t, out) is non-temporal so the ~160 KB
// coefficient tables stay cache-resident. t is sorted => per-wave gathers
// are near-broadcast.

typedef float v2f __attribute__((ext_vector_type(2)));
typedef float v4f __attribute__((ext_vector_type(4)));

__global__ __launch_bounds__(256) void spline_eval(
    const v2f* __restrict__ t2,         // t viewed as float-vec2
    const float4* __restrict__ ctrl4,   // (S,): p1x,p1y,p2x,p2y per segment
    const float2* __restrict__ joint2,  // (S+1,)
    v4f* __restrict__ out4,             // out viewed as float-vec4, 1/thread
    int n2, int n, float Sf, int Smax)  // n2 = ceil(n/2), Smax = S-1
{
    int i = blockIdx.x * blockDim.x + threadIdx.x;
    if (i >= n2) return;

    v2f tv = __builtin_nontemporal_load(&t2[i]);
    float ts[2] = {tv.x, tv.y};
    float rx[2], ry[2];

#pragma unroll
    for (int j = 0; j < 2; ++j) {
        // parity: jnp.minimum(t, 1.0-1e-10) -> fp32 min(t, 1.0f)
        float tt = fminf(ts[j], 1.0f);
        float u = Sf * tt;
        float segf = floorf(u);
        float lt = u - segf;
        int seg = (int)segf;
        if (seg > Smax) {          // reference's over-clamp (seg == S)
            seg = Smax;
            lt = 1.0f;
        }
        float2 p0 = joint2[seg];
        float2 p3 = joint2[seg + 1];
        float4 c  = ctrl4[seg];    // p1 = (c.x,c.y), p2 = (c.z,c.w)

        // power-basis coefficients (== BEZIER_M @ pts)
        float c1x = 3.0f * (c.x - p0.x);
        float c2x = 3.0f * (p0.x - 2.0f * c.x + c.z);
        float c3x = (p3.x - p0.x) + 3.0f * (c.x - c.z);
        float c1y = 3.0f * (c.y - p0.y);
        float c2y = 3.0f * (p0.y - 2.0f * c.y + c.w);
        float c3y = (p3.y - p0.y) + 3.0f * (c.y - c.w);

        rx[j] = fmaf(lt, fmaf(lt, fmaf(lt, c3x, c2x), c1x), p0.x);
        ry[j] = fmaf(lt, fmaf(lt, fmaf(lt, c3y, c2y), c1y), p0.y);
    }

    int base = 2 * i;
    if (base + 2 <= n) {
        v4f res = {rx[0], ry[0], rx[1], ry[1]};
        __builtin_nontemporal_store(res, &out4[i]);
    } else {
        // odd-N tail (not hit for N = 8388608)
        float* out = reinterpret_cast<float*>(out4);
        out[2 * base]     = rx[0];
        out[2 * base + 1] = ry[0];
    }
}

extern "C" void kernel_launch(void* const* d_in, const int* in_sizes, int n_in,
                              void* d_out, int out_size, void* d_ws, size_t ws_size,
                              hipStream_t stream) {
    const float* t     = (const float*)d_in[0];
    const float* ctrl  = (const float*)d_in[1];  // (S*2, 2)
    const float* joint = (const float*)d_in[2];  // (S+1, 2)
    float* out = (float*)d_out;

    int n = in_sizes[0];
    int S = in_sizes[2] / 2 - 1;

    int n2 = (n + 1) / 2;
    int block = 256;
    int grid = (n2 + block - 1) / block;

    spline_eval<<<grid, block, 0, stream>>>(
        reinterpret_cast<const v2f*>(t),
        reinterpret_cast<const float4*>(ctrl),
        reinterpret_cast<const float2*>(joint),
        reinterpret_cast<v4f*>(out),
        n2, n, (float)S, S - 1);
}

// Round 4
// 96.632 us; speedup vs baseline: 1.1029x; 1.1029x over previous
//
#include <hip/hip_runtime.h>

// Cubic Bezier spline evaluation, round 4.
// t: (N,) SORTED fp32 in [0,1); ctrl: (S*2, 2) fp32; joint: (S+1, 2) fp32.
// out: (N, 2) fp32.
//
// Key exploit: t is sorted, so ~94% of waves (128 consecutive samples,
// avg segment covers 2048 samples) lie entirely inside ONE segment. For
// those waves the segment gather + power-basis coefficient assembly is
// wave-uniform -> scalar loads + scalar math once per wave, leaving only
// t-load / 6 FMA / store in the per-lane hot path. Boundary waves (~6%)
// and the partial tail wave fall back to per-lane gathers.
// All NT cache hints removed (round-3 experiment: neutral-to-negative).

typedef float v2f __attribute__((ext_vector_type(2)));
typedef float v4f __attribute__((ext_vector_type(4)));

__global__ __launch_bounds__(256) void spline_eval(
    const v2f* __restrict__ t2,         // t viewed as float-vec2
    const float4* __restrict__ ctrl4,   // (S,): p1x,p1y,p2x,p2y per segment
    const float2* __restrict__ joint2,  // (S+1,)
    v4f* __restrict__ out4,             // out viewed as float-vec4, 1/thread
    int n2, int n, float Sf, int Smax)  // n2 = ceil(n/2), Smax = S-1
{
    int i = blockIdx.x * blockDim.x + threadIdx.x;
    if (i >= n2) return;

    v2f tv = t2[i];
    float lt[2];
    int   seg[2];

#pragma unroll
    for (int j = 0; j < 2; ++j) {
        // parity: jnp.minimum(t, 1.0-1e-10) -> fp32 min(t, 1.0f)
        float tt = fminf(j == 0 ? tv.x : tv.y, 1.0f);
        float u = Sf * tt;
        float sf = floorf(u);
        float l = u - sf;
        int s = (int)sf;
        if (s > Smax) {            // reference's over-clamp (seg == S)
            s = Smax;
            l = 1.0f;
        }
        seg[j] = s;
        lt[j] = l;
    }

    float rx[2], ry[2];

    int s0 = __builtin_amdgcn_readfirstlane(seg[0]);
    bool mine_uniform = (seg[0] == s0) & (seg[1] == s0);
    // Full wave in one segment? (partial tail wave fails the ==~0 check
    // since inactive lanes contribute 0 bits -> takes the gather path)
    if (__ballot(mine_uniform) == ~0ull) {
        // --- wave-uniform fast path: scalar gather + scalar coeffs ---
        float2 p0 = joint2[s0];
        float2 p3 = joint2[s0 + 1];
        float4 c  = ctrl4[s0];     // p1 = (c.x,c.y), p2 = (c.z,c.w)

        float c1x = 3.0f * (c.x - p0.x);
        float c2x = 3.0f * (p0.x - 2.0f * c.x + c.z);
        float c3x = (p3.x - p0.x) + 3.0f * (c.x - c.z);
        float c1y = 3.0f * (c.y - p0.y);
        float c2y = 3.0f * (p0.y - 2.0f * c.y + c.w);
        float c3y = (p3.y - p0.y) + 3.0f * (c.y - c.w);

#pragma unroll
        for (int j = 0; j < 2; ++j) {
            float l = lt[j];
            rx[j] = fmaf(l, fmaf(l, fmaf(l, c3x, c2x), c1x), p0.x);
            ry[j] = fmaf(l, fmaf(l, fmaf(l, c3y, c2y), c1y), p0.y);
        }
    } else {
        // --- boundary / tail path: per-lane gathers ---
#pragma unroll
        for (int j = 0; j < 2; ++j) {
            int s = seg[j];
            float l = lt[j];
            float2 p0 = joint2[s];
            float2 p3 = joint2[s + 1];
            float4 c  = ctrl4[s];

            float c1x = 3.0f * (c.x - p0.x);
            float c2x = 3.0f * (p0.x - 2.0f * c.x + c.z);
            float c3x = (p3.x - p0.x) + 3.0f * (c.x - c.z);
            float c1y = 3.0f * (c.y - p0.y);
            float c2y = 3.0f * (p0.y - 2.0f * c.y + c.w);
            float c3y = (p3.y - p0.y) + 3.0f * (c.y - c.w);

            rx[j] = fmaf(l, fmaf(l, fmaf(l, c3x, c2x), c1x), p0.x);
            ry[j] = fmaf(l, fmaf(l, fmaf(l, c3y, c2y), c1y), p0.y);
        }
    }

    int base = 2 * i;
    if (base + 2 <= n) {
        v4f res = {rx[0], ry[0], rx[1], ry[1]};
        out4[i] = res;
    } else {
        // odd-N tail (not hit for N = 8388608)
        float* out = reinterpret_cast<float*>(out4);
        out[2 * base]     = rx[0];
        out[2 * base + 1] = ry[0];
    }
}

extern "C" void kernel_launch(void* const* d_in, const int* in_sizes, int n_in,
                              void* d_out, int out_size, void* d_ws, size_t ws_size,
                              hipStream_t stream) {
    const float* t     = (const float*)d_in[0];
    const float* ctrl  = (const float*)d_in[1];  // (S*2, 2)
    const float* joint = (const float*)d_in[2];  // (S+1, 2)
    float* out = (float*)d_out;

    int n = in_sizes[0];
    int S = in_sizes[2] / 2 - 1;

    int n2 = (n + 1) / 2;
    int block = 256;
    int grid = (n2 + block - 1) / block;

    spline_eval<<<grid, block, 0, stream>>>(
        reinterpret_cast<const v2f*>(t),
        reinterpret_cast<const float4*>(ctrl),
        reinterpret_cast<const float2*>(joint),
        reinterpret_cast<v4f*>(out),
        n2, n, (float)S, S - 1);
}